// Round 2
// baseline (833.811 us; speedup 1.0000x reference)
//
#include <hip/hip_runtime.h>
#include <hip/hip_bf16.h>

#define MM 2048
#define CC 64
#define NEG_EPS_INV (-10.0f)   // -1/EPS, EPS=0.1

// ---------------------------------------------------------------------------
// k_tr: seq2t[b][n][c] = feat2[b][c][n]   (64x64 LDS transpose tiles)
// ---------------------------------------------------------------------------
__global__ __launch_bounds__(256) void k_tr(const float* __restrict__ f2,
                                            float* __restrict__ s2t) {
    __shared__ float t[64 * 65];
    int bx = blockIdx.x;
    int b = bx >> 5, nc = bx & 31;
    int tid = threadIdx.x;
    int col = tid & 63, cp = tid >> 6;
    const size_t fbase = (size_t)b * CC * MM;
    for (int it = 0; it < 16; ++it) {
        int c = it * 4 + cp;
        t[c * 65 + col] = f2[fbase + (size_t)c * MM + nc * 64 + col];
    }
    __syncthreads();
    int w = tid >> 6, lane = tid & 63;
    for (int i = 0; i < 16; ++i) {
        int nn = w * 16 + i;
        s2t[((size_t)b * MM + nc * 64 + nn) * 64 + lane] = t[lane * 65 + nn];
    }
}

// ---------------------------------------------------------------------------
// k_build: K0[b][m][n] = -max(sq1[m]+sq2[n]-2*cross,0)/eps  (+ optional K0T)
// grid: b(2) x mt(32) x nt(32) = 2048 blocks, 256 threads
// ---------------------------------------------------------------------------
__global__ __launch_bounds__(256) void k_build(const float* __restrict__ f1,
                                               const float* __restrict__ f2,
                                               float* __restrict__ K0,
                                               float* __restrict__ K0T, int useT) {
    __shared__ float f1s[64 * 64];
    __shared__ float f2s[64 * 64];
    __shared__ float kt[64 * 65];
    __shared__ float sq1s[64], sq2s[64];
    int bx = blockIdx.x;
    int b = bx >> 10, mt = (bx >> 5) & 31, nt = bx & 31;
    int tid = threadIdx.x;
    int w = tid >> 6, lane = tid & 63;
    int col = tid & 63, cp = tid >> 6;
    const size_t fbase = (size_t)b * CC * MM;
    for (int it = 0; it < 16; ++it) {
        int c = it * 4 + cp;
        f1s[c * 64 + col] = f1[fbase + (size_t)c * MM + mt * 64 + col];
        f2s[c * 64 + col] = f2[fbase + (size_t)c * MM + nt * 64 + col];
    }
    __syncthreads();
    if (tid < 64) {
        float s = 0.f;
        for (int c = 0; c < 64; ++c) { float x = f1s[c * 64 + tid]; s = fmaf(x, x, s); }
        sq1s[tid] = s;
    } else if (tid < 128) {
        int n = tid - 64;
        float s = 0.f;
        for (int c = 0; c < 64; ++c) { float x = f2s[c * 64 + n]; s = fmaf(x, x, s); }
        sq2s[n] = s;
    }
    __syncthreads();
    float acc[16];
#pragma unroll
    for (int i = 0; i < 16; ++i) acc[i] = 0.f;
    for (int c = 0; c < 64; ++c) {
        float f2v = f2s[c * 64 + lane];
#pragma unroll
        for (int i = 0; i < 16; ++i)
            acc[i] = fmaf(f1s[c * 64 + w * 16 + i], f2v, acc[i]);
    }
    float sq2v = sq2s[lane];
    size_t kbase = ((size_t)b * MM + mt * 64 + w * 16) * MM + nt * 64 + lane;
#pragma unroll
    for (int i = 0; i < 16; ++i) {
        float r = sq1s[w * 16 + i] + sq2v - 2.f * acc[i];
        r = fmaxf(r, 0.f);
        float kv = NEG_EPS_INV * r;
        K0[kbase + (size_t)i * MM] = kv;
        kt[(w * 16 + i) * 65 + lane] = kv;
    }
    if (useT) {
        __syncthreads();
        size_t tbase = ((size_t)b * MM + nt * 64 + w * 16) * MM + mt * 64 + lane;
#pragma unroll
        for (int i = 0; i < 16; ++i)
            K0T[tbase + (size_t)i * MM] = kt[lane * 65 + (w * 16 + i)];
    }
}

// ---------------------------------------------------------------------------
// k_lse: uout[b][m] = -logsumexp_n(K[b][m][n] + vin[b][n])
// grid: 1024 blocks (2 x 512), 256 threads, one wave per row
// ---------------------------------------------------------------------------
__global__ __launch_bounds__(256) void k_lse(const float* __restrict__ K,
                                             const float* __restrict__ vin,
                                             float* __restrict__ uout) {
    int bx = blockIdx.x;
    int b = bx >> 9, rg = bx & 511;
    int w = threadIdx.x >> 6, lane = threadIdx.x & 63;
    int m = rg * 4 + w;
    const float* rowp = K + ((size_t)b * MM + m) * MM;
    const float* vp = vin + (size_t)b * MM;
    float x[32];
#pragma unroll
    for (int j = 0; j < 8; ++j) {
        float4 kv = *(const float4*)(rowp + j * 256 + lane * 4);
        float4 vv = *(const float4*)(vp + j * 256 + lane * 4);
        x[j * 4 + 0] = kv.x + vv.x;
        x[j * 4 + 1] = kv.y + vv.y;
        x[j * 4 + 2] = kv.z + vv.z;
        x[j * 4 + 3] = kv.w + vv.w;
    }
    float mx = x[0];
#pragma unroll
    for (int i = 1; i < 32; ++i) mx = fmaxf(mx, x[i]);
#pragma unroll
    for (int off = 32; off >= 1; off >>= 1) mx = fmaxf(mx, __shfl_xor(mx, off));
    float s = 0.f;
#pragma unroll
    for (int i = 0; i < 32; ++i) s += __expf(x[i] - mx);
#pragma unroll
    for (int off = 32; off >= 1; off >>= 1) s += __shfl_xor(s, off);
    if (lane == 0) uout[(size_t)b * MM + m] = -(mx + __logf(s));
}

// ---------------------------------------------------------------------------
// k_colfb: fallback column pass without transpose (coalesced col-chunk reads)
// vout[b][n] = -logsumexp_m(K[b][m][n] + uin[b][m])
// grid: 64 blocks (2 x 32), 1024 threads (16 waves split m)
// ---------------------------------------------------------------------------
__global__ __launch_bounds__(1024) void k_colfb(const float* __restrict__ K,
                                                const float* __restrict__ uin,
                                                float* __restrict__ vout) {
    __shared__ float pm[16 * 64], ps[16 * 64];
    int bx = blockIdx.x;
    int b = bx >> 5, nc = bx & 31;
    int w = threadIdx.x >> 6, lane = threadIdx.x & 63;
    int n = nc * 64 + lane;
    const float* up = uin + (size_t)b * MM;
    float mx = -3.0e38f, s = 0.f;
    size_t base = ((size_t)b * MM + w * 128) * MM + n;
    for (int mm = 0; mm < 128; ++mm) {
        float x = K[base + (size_t)mm * MM] + up[w * 128 + mm];
        float nm = fmaxf(mx, x);
        s = s * __expf(mx - nm) + __expf(x - nm);
        mx = nm;
    }
    pm[w * 64 + lane] = mx;
    ps[w * 64 + lane] = s;
    __syncthreads();
    if (w == 0) {
        float M2 = pm[lane];
        for (int i = 1; i < 16; ++i) M2 = fmaxf(M2, pm[i * 64 + lane]);
        float S = 0.f;
        for (int i = 0; i < 16; ++i) S += ps[i * 64 + lane] * __expf(pm[i * 64 + lane] - M2);
        vout[(size_t)b * MM + n] = -(M2 + __logf(S));
    }
}

// ---------------------------------------------------------------------------
// k_fot: fot[b][m][c] += sum_n exp(K0+u+v) * seq2t[b][n][c]   (n-split, atomics)
// grid: 512 blocks (2 x 64 mgroups x 4 nsegs), 256 threads, 64KB dyn LDS
// ---------------------------------------------------------------------------
__global__ __launch_bounds__(256) void k_fot(const float* __restrict__ K0,
                                             const float* __restrict__ u,
                                             const float* __restrict__ v,
                                             const float* __restrict__ s2t,
                                             float* __restrict__ fot) {
    extern __shared__ float plds[];  // [4 waves][512 n][8 r]
    int bx = blockIdx.x;
    int b = bx >> 8, mg = (bx >> 2) & 63, ns = bx & 3;
    int w = threadIdx.x >> 6, lane = threadIdx.x & 63;
    int m0 = mg * 32 + w * 8;
    float* pw = plds + w * 512 * 8;
    const float* vp = v + (size_t)b * MM + ns * 512;
#pragma unroll
    for (int r = 0; r < 8; ++r) {
        const float* krow = K0 + ((size_t)b * MM + m0 + r) * MM + ns * 512;
        float uv = u[(size_t)b * MM + m0 + r];
        for (int j = 0; j < 8; ++j) {
            int nn = j * 64 + lane;
            pw[nn * 8 + r] = __expf(krow[nn] + uv + vp[nn]);
        }
    }
    __syncthreads();
    float acc[8];
#pragma unroll
    for (int r = 0; r < 8; ++r) acc[r] = 0.f;
    const float* s2p = s2t + ((size_t)b * MM + ns * 512) * 64 + lane;
    for (int nn = 0; nn < 512; ++nn) {
        float s2 = s2p[(size_t)nn * 64];
        float4 p0 = *(const float4*)(pw + nn * 8);
        float4 p1 = *(const float4*)(pw + nn * 8 + 4);
        acc[0] = fmaf(p0.x, s2, acc[0]);
        acc[1] = fmaf(p0.y, s2, acc[1]);
        acc[2] = fmaf(p0.z, s2, acc[2]);
        acc[3] = fmaf(p0.w, s2, acc[3]);
        acc[4] = fmaf(p1.x, s2, acc[4]);
        acc[5] = fmaf(p1.y, s2, acc[5]);
        acc[6] = fmaf(p1.z, s2, acc[6]);
        acc[7] = fmaf(p1.w, s2, acc[7]);
    }
#pragma unroll
    for (int r = 0; r < 8; ++r)
        atomicAdd(&fot[((size_t)b * MM + m0 + r) * 64 + lane], acc[r]);
}

// ---------------------------------------------------------------------------
// k_gate: h=relu(W1@cat+b1); g=sigmoid(W2@h+b2); out=g*f1+(1-g)*fot
// grid: 1024 blocks (2 x 512), 256 threads, one wave per m-column
// ---------------------------------------------------------------------------
__global__ __launch_bounds__(256) void k_gate(const float* __restrict__ f1,
                                              const float* __restrict__ fot,
                                              const float* __restrict__ w1,
                                              const float* __restrict__ b1,
                                              const float* __restrict__ w2,
                                              const float* __restrict__ b2,
                                              float* __restrict__ out) {
    __shared__ float w1s[64 * 129];
    __shared__ float w2s[64 * 65];
    __shared__ float cats[4 * 128];
    __shared__ float hs[4 * 64];
    __shared__ float outs[64 * 5];
    int bx = blockIdx.x;
    int b = bx >> 9, mg = bx & 511;
    int tid = threadIdx.x;
    int w = tid >> 6, lane = tid & 63;
    int m = mg * 4 + w;
    for (int t = 0; t < 32; ++t) {
        int idx = t * 256 + tid;
        w1s[(idx >> 7) * 129 + (idx & 127)] = w1[idx];
    }
    for (int t = 0; t < 16; ++t) {
        int idx = t * 256 + tid;
        w2s[(idx >> 6) * 65 + (idx & 63)] = w2[idx];
    }
    float f1v = f1[(size_t)b * CC * MM + (size_t)lane * MM + m];
    float fov = fot[((size_t)b * MM + m) * 64 + lane];
    cats[w * 128 + lane] = f1v;
    cats[w * 128 + 64 + lane] = fov;
    __syncthreads();
    float hacc = b1[lane];
    for (int c = 0; c < 128; ++c)
        hacc = fmaf(w1s[lane * 129 + c], cats[w * 128 + c], hacc);
    hs[w * 64 + lane] = fmaxf(hacc, 0.f);
    __syncthreads();
    float g = b2[lane];
    for (int c = 0; c < 64; ++c)
        g = fmaf(w2s[lane * 65 + c], hs[w * 64 + c], g);
    g = 1.f / (1.f + __expf(-g));
    float fused = g * f1v + (1.f - g) * fov;
    outs[lane * 5 + w] = fused;
    __syncthreads();
    int o = tid >> 2, mi = tid & 3;
    out[(size_t)b * CC * MM + (size_t)o * MM + mg * 4 + mi] = outs[o * 5 + mi];
}

// ---------------------------------------------------------------------------
extern "C" void kernel_launch(void* const* d_in, const int* in_sizes, int n_in,
                              void* d_out, int out_size, void* d_ws, size_t ws_size,
                              hipStream_t stream) {
    const float* feat1 = (const float*)d_in[0];
    const float* feat2 = (const float*)d_in[1];
    const float* w1 = (const float*)d_in[2];
    const float* b1 = (const float*)d_in[3];
    const float* w2 = (const float*)d_in[4];
    const float* b2 = (const float*)d_in[5];
    float* out = (float*)d_out;
    char* ws = (char*)d_ws;

    const size_t S = (size_t)2 * MM * MM * 4;                      // 33,554,432 B
    const size_t tail = 16384 + 16384 + 1048576 + 1048576;         // u,v,s2t,fot
    int useT = (ws_size >= 2 * S + tail) ? 1 : 0;

    float* K0 = (float*)ws;
    float* K0T = (float*)(ws + S);
    float* tailp = (float*)(ws + (useT ? 2 * S : S));
    float* u = tailp;
    float* v = tailp + 4096;
    float* s2t = v + 4096;
    float* fot = s2t + 262144;

    k_tr<<<64, 256, 0, stream>>>(feat2, s2t);
    k_build<<<2048, 256, 0, stream>>>(feat1, feat2, K0, K0T, useT);
    hipMemsetAsync(v, 0, 16384, stream);
    hipMemsetAsync(fot, 0, 1048576, stream);

    for (int it = 0; it < 50; ++it) {
        k_lse<<<1024, 256, 0, stream>>>(K0, v, u);
        if (useT)
            k_lse<<<1024, 256, 0, stream>>>(K0T, u, v);
        else
            k_colfb<<<64, 1024, 0, stream>>>(K0, u, v);
    }

    k_fot<<<512, 256, 65536, stream>>>(K0, u, v, s2t, fot);
    k_gate<<<1024, 256, 0, stream>>>(feat1, fot, w1, b1, w2, b2, out);
}